// Round 2
// baseline (4789.653 us; speedup 1.0000x reference)
//
#include <hip/hip_runtime.h>
#include <hip/hip_bf16.h>

// Bi-LSTM persistent kernel v5.1. B=32, T=512, D=H=512.
// 4 sync groups = dir(2) x batch-half(2); 32 WGs/group, 16 rows/group, 16 h-cols/WG.
// Sync: NO flags, NO producer drain. Each h element is a self-validating tagged
// u32 {hi16 = step+1, lo16 = bf16 h}. Producers fire-and-forget dword stores;
// consumers poll the data itself and verify every tag (per-dword atomicity makes
// torn snapshots detectable + retried).
// v5.1 vs v5: incremental load+check+pack (8-VGPR transient instead of 64 live
// u64s -> no register spike / no scratch in the spin loop), s_sleep(1) on retry.
#define Bz 32
#define Tz 512
#define Dz 512
#define Hz 512
#define NG 4      // sync groups
#define GWG 32    // workgroups per group
#define ROWS 16   // batch rows per group (one MFMA m-tile)
#define COLS 16   // h-cols per WG

typedef __attribute__((ext_vector_type(8))) short short8;
typedef __attribute__((ext_vector_type(4))) float f32x4;
typedef __attribute__((ext_vector_type(4))) unsigned int u32x4;

#define HBUF (ROWS * Hz * 4)                 // 32 KB tagged u32 per (group,parity)
#define WS_H 0
#define WS_X (NG * 2 * HBUF)                 // 256 KB of h buffers
#define WS_NEED ((size_t)WS_X + (size_t)Bz * Tz * Dz * 2)

__device__ __forceinline__ unsigned short f2bf(float f) {
    return __builtin_bit_cast(unsigned short, __float2bfloat16(f));
}
__device__ __forceinline__ float rcp_(float x) { return __builtin_amdgcn_rcpf(x); }
__device__ __forceinline__ float fsig(float x) { return rcp_(1.0f + __expf(-x)); }
__device__ __forceinline__ float ftanh(float x) {
    float t = __expf(-2.0f * fabsf(x));
    return copysignf((1.0f - t) * rcp_(1.0f + t), x);
}

__global__ void init_kernel(const float* __restrict__ x, unsigned char* __restrict__ ws, int do_x) {
    int tid = blockIdx.x * blockDim.x + threadIdx.x;
    unsigned int* w32 = (unsigned int*)ws;
    if (tid < (WS_X / 4)) w32[tid] = 0u;   // all h buffers: tag 0 == "h(-1) ready", value 0
    if (do_x) {
        const int n4 = (Bz * Tz * Dz) / 4;
        if (tid < n4) {
            const float4* xin = (const float4*)x;
            float4 v = xin[tid];
            unsigned int u0 = (unsigned)f2bf(v.x) | ((unsigned)f2bf(v.y) << 16);
            unsigned int u1 = (unsigned)f2bf(v.z) | ((unsigned)f2bf(v.w) << 16);
            unsigned int* xo = (unsigned int*)(ws + WS_X);
            xo[tid * 2]     = u0;
            xo[tid * 2 + 1] = u1;
        }
    }
}

template <bool XB>
__launch_bounds__(256, 1)
__global__ void lstm_kernel(const float* __restrict__ xf,
                            const float* __restrict__ Wf, const float* __restrict__ bf,
                            const float* __restrict__ Wb, const float* __restrict__ bb,
                            float* __restrict__ out, unsigned char* __restrict__ ws) {
    const int bi   = blockIdx.x;
    const int dir  = bi & 1;
    const int grp  = (bi >> 1) & 1;
    const int wg   = bi >> 2;            // 0..31
    const int gid  = dir * 2 + grp;
    const int j0   = wg * COLS;
    const int b0   = grp * ROWS;
    const int tid  = threadIdx.x;
    const int wave = tid >> 6;
    const int lane = tid & 63;
    const int nidx = lane & 15;          // B-frag col n / A-frag row m
    const int quad = lane >> 4;

    const float* W    = dir ? Wb : Wf;
    const float* bias = dir ? bb : bf;

    unsigned char* hbase = ws + WS_H + gid * 2 * HBUF;              // + parity*HBUF
    const unsigned short* xbf = (const unsigned short*)(ws + WS_X);

    // double-buffered partials -> single __syncthreads per step
    __shared__ float part[2][4][4][16][17];  // parity, wave, gate, row, col (+1 pad)

    // --- one-time: W slice as B-fragments in registers (bf16) ---
    // wave 0/1: K rows [0,256)/[256,512) of Wx; wave 2/3: rows [0,256)/[256,512) of Wh.
    short8 bfrag[8][4];
    {
        const int krow0 = (wave < 2) ? wave * 256 : 512 + (wave - 2) * 256;
        #pragma unroll
        for (int i = 0; i < 8; ++i) {
            #pragma unroll
            for (int g = 0; g < 4; ++g) {
                short8 v;
                #pragma unroll
                for (int jj = 0; jj < 8; ++jj) {
                    int krow = krow0 + i * 32 + quad * 8 + jj;
                    v[jj] = (short)f2bf(W[krow * (4 * Hz) + g * 512 + j0 + nidx]);
                }
                bfrag[i][g] = v;
            }
        }
    }

    // --- per-thread epilogue state: one (row,col) each ---
    const int erow = tid >> 4;
    const int ecol = tid & 15;
    float bia[4];
    #pragma unroll
    for (int g = 0; g < 4; ++g) bia[g] = bias[g * 512 + j0 + ecol];
    float creg = 0.f;
    const size_t outbase = ((size_t)(b0 + erow) * Tz) * (2 * Hz) + dir * Hz + j0 + ecol;

    for (int s = 0; s < Tz; ++s) {
        const int t   = dir ? (Tz - 1 - s) : s;
        const int par = s & 1;
        f32x4 acc[4] = {{0,0,0,0},{0,0,0,0},{0,0,0,0},{0,0,0,0}};

        if (wave < 2) {
            // x part — independent of h, overlaps consumers' polling.
            const int kb = wave * 256;
            short8 a[8];
            if (XB) {
                #pragma unroll
                for (int i = 0; i < 8; ++i) {
                    int k = kb + i * 32 + quad * 8;
                    a[i] = *(const short8*)(xbf + (((b0 + nidx) * Tz + t) * Dz + k));
                }
            } else {
                #pragma unroll
                for (int i = 0; i < 8; ++i) {
                    int k = kb + i * 32 + quad * 8;
                    const float* q = xf + (((b0 + nidx) * Tz + t) * Dz + k);
                    short8 sv;
                    #pragma unroll
                    for (int jj = 0; jj < 8; ++jj) sv[jj] = (short)f2bf(q[jj]);
                    a[i] = sv;
                }
            }
            #pragma unroll
            for (int i = 0; i < 8; ++i)
                #pragma unroll
                for (int g = 0; g < 4; ++g)
                    acc[g] = __builtin_amdgcn_mfma_f32_16x16x32_bf16(a[i], bfrag[i][g], acc[g], 0, 0, 0);
        } else {
            // h part: poll the tagged data directly. When every tag of this wave's
            // K-half reads s, the loaded words ARE h(s-1) — no flag, no extra RT.
            // Incremental: per-fragment load (4 u64) -> tag-fold -> pack, so only
            // ~8 transient VGPRs beyond a[8] live across the retry loop.
            const int kb = (wave - 2) * 256;
            const unsigned long long* hb64 = (const unsigned long long*)(hbase + par * HBUF);
            const unsigned txor = ((unsigned)s) << 16;
            short8 a[8];
            for (;;) {
                unsigned bad = 0;
                #pragma unroll
                for (int i = 0; i < 8; ++i) {
                    const int k = kb + i * 32 + quad * 8;
                    const unsigned long long* p = hb64 + ((nidx * Hz + k) >> 1);
                    u32x4 w;
                    #pragma unroll
                    for (int q = 0; q < 4; ++q) {
                        unsigned long long r = __hip_atomic_load(p + q, __ATOMIC_RELAXED, __HIP_MEMORY_SCOPE_AGENT);
                        unsigned lo = (unsigned)r;
                        unsigned hi = (unsigned)(r >> 32);
                        bad |= lo ^ txor;
                        bad |= hi ^ txor;
                        w[q] = __builtin_amdgcn_perm(hi, lo, 0x05040100u);
                    }
                    a[i] = __builtin_bit_cast(short8, w);
                }
                if (__ballot((bad >> 16) == 0) == ~0ull) break;
                __builtin_amdgcn_s_sleep(1);
            }
            #pragma unroll
            for (int i = 0; i < 8; ++i)
                #pragma unroll
                for (int g = 0; g < 4; ++g)
                    acc[g] = __builtin_amdgcn_mfma_f32_16x16x32_bf16(a[i], bfrag[i][g], acc[g], 0, 0, 0);
        }

        // C/D layout: col = lane&15, row = quad*4 + reg
        {
            const int r0 = quad * 4;
            #pragma unroll
            for (int g = 0; g < 4; ++g)
                #pragma unroll
                for (int r = 0; r < 4; ++r)
                    part[par][wave][g][r0 + r][nidx] = acc[g][r];
        }
        __syncthreads();

        // epilogue: one (row,col) per thread
        {
            float z[4];
            #pragma unroll
            for (int g = 0; g < 4; ++g)
                z[g] = bia[g] + part[par][0][g][erow][ecol] + part[par][1][g][erow][ecol]
                             + part[par][2][g][erow][ecol] + part[par][3][g][erow][ecol];
            float c = fsig(z[1]) * creg + fsig(z[0]) * ftanh(z[3]);
            creg = c;
            float hv = fsig(z[2]) * ftanh(c);
            // fire-and-forget tagged store: {tag = s+1, bf16 h}. No drain, no flag.
            unsigned* hw = (unsigned*)(hbase + (par ^ 1) * HBUF);
            unsigned d = (unsigned)f2bf(hv) | ((unsigned)(s + 1) << 16);
            __hip_atomic_store(hw + erow * Hz + (j0 + ecol), d,
                               __ATOMIC_RELAXED, __HIP_MEMORY_SCOPE_AGENT);
            // out store after the h publish: its HBM ack overlaps the next step.
            out[outbase + (size_t)t * (2 * Hz)] = hv;
        }
        // no second barrier: LDS partials are double-buffered, h reuse is guarded
        // by the tag protocol itself.
    }
}

extern "C" void kernel_launch(void* const* d_in, const int* in_sizes, int n_in,
                              void* d_out, int out_size, void* d_ws, size_t ws_size,
                              hipStream_t stream) {
    const float* x  = (const float*)d_in[0];
    const float* Wf = (const float*)d_in[1];
    const float* bf = (const float*)d_in[2];
    const float* Wb = (const float*)d_in[3];
    const float* bb = (const float*)d_in[4];
    float* out = (float*)d_out;
    unsigned char* ws = (unsigned char*)d_ws;
    const bool xb = (ws_size >= WS_NEED);

    init_kernel<<<8192, 256, 0, stream>>>(x, ws, xb ? 1 : 0);
    if (xb)
        lstm_kernel<true><<<NG * GWG, 256, 0, stream>>>(x, Wf, bf, Wb, bb, out, ws);
    else
        lstm_kernel<false><<<NG * GWG, 256, 0, stream>>>(x, Wf, bf, Wb, bb, out, ws);
}

// Round 6
// 2145.483 us; speedup vs baseline: 2.2324x; 2.2324x over previous
//
#include <hip/hip_runtime.h>
#include <hip/hip_bf16.h>

// Bi-LSTM persistent kernel v7. B=32, T=512, D=H=512.
// Geometry = v4 (proven): 4 sync groups = dir(2) x batch-half(2); 32 WGs/group,
// 16 rows/group, 16 h-cols/WG; 128 blocks. Sync = v4 flag protocol (agent-scope
// relaxed atomics, drain-then-flag).
// v7 structural changes (all plain-HIP / previously-passing constructs):
//  - Wave specialization: waves 0/1 do x-GEMM + epilogue (2 cols/thread,
//    in-thread col pair -> no shfl, float2 out store) + h-store + drain +
//    flag publish. Waves 2/3 do ONLY flag-poll + h-load + h-MFMA and free-run
//    into the next step's poll while waves 0/1 finish the epilogue tail.
//  - Single __syncthreads per step (parity double-buffered LDS partials);
//    cross-wave drain ordering via a 2-party LDS handshake (waves 0/1).
//  - Each h-wave polls only its own 16 producers (wave2: flags 0-15 = cols
//    0-255; wave3: flags 16-31), halving the straggler set.
//  - Tight poll (no s_sleep quantization).
#define Bz 32
#define Tz 512
#define Dz 512
#define Hz 512
#define NG 4      // sync groups
#define GWG 32    // workgroups per group
#define ROWS 16   // batch rows per group (one MFMA m-tile)
#define COLS 16   // h-cols per WG

typedef __attribute__((ext_vector_type(8))) short short8;
typedef __attribute__((ext_vector_type(4))) short short4v;
typedef __attribute__((ext_vector_type(4))) float f32x4;

#define HBUF (ROWS * Hz * 2)                 // 16 KB per (group,parity)
#define FLGB 512                             // 32 flags @ 16B stride per group
#define WS_FLG 0                             // NG * 512 B
#define WS_H   (NG * FLGB)
#define WS_X   (WS_H + NG * 2 * HBUF)        // x in bf16: 16 MB
#define WS_NEED ((size_t)WS_X + (size_t)Bz * Tz * Dz * 2)

__device__ __forceinline__ unsigned short f2bf(float f) {
    return __builtin_bit_cast(unsigned short, __float2bfloat16(f));
}
__device__ __forceinline__ float rcp_(float x) { return __builtin_amdgcn_rcpf(x); }
__device__ __forceinline__ float fsig(float x) { return rcp_(1.0f + __expf(-x)); }
__device__ __forceinline__ float ftanh(float x) {
    float t = __expf(-2.0f * fabsf(x));
    return copysignf((1.0f - t) * rcp_(1.0f + t), x);
}
__device__ __forceinline__ short8 mk8(unsigned long long lo, unsigned long long hi) {
    short4v a = __builtin_bit_cast(short4v, lo);
    short4v b = __builtin_bit_cast(short4v, hi);
    short8 r;
    r[0]=a[0]; r[1]=a[1]; r[2]=a[2]; r[3]=a[3];
    r[4]=b[0]; r[5]=b[1]; r[6]=b[2]; r[7]=b[3];
    return r;
}

__global__ void init_kernel(const float* __restrict__ x, unsigned char* __restrict__ ws, int do_x) {
    int tid = blockIdx.x * blockDim.x + threadIdx.x;
    unsigned int* w32 = (unsigned int*)ws;
    if (tid < (WS_X / 4)) w32[tid] = 0u;   // flags + all h buffers
    if (do_x) {
        const int n4 = (Bz * Tz * Dz) / 4;
        if (tid < n4) {
            const float4* xin = (const float4*)x;
            float4 v = xin[tid];
            unsigned int u0 = (unsigned)f2bf(v.x) | ((unsigned)f2bf(v.y) << 16);
            unsigned int u1 = (unsigned)f2bf(v.z) | ((unsigned)f2bf(v.w) << 16);
            unsigned int* xo = (unsigned int*)(ws + WS_X);
            xo[tid * 2]     = u0;
            xo[tid * 2 + 1] = u1;
        }
    }
}

template <bool XB>
__launch_bounds__(256, 1)
__global__ void lstm_kernel(const float* __restrict__ xf,
                            const float* __restrict__ Wf, const float* __restrict__ bf,
                            const float* __restrict__ Wb, const float* __restrict__ bb,
                            float* __restrict__ out, unsigned char* __restrict__ ws) {
    const int bi   = blockIdx.x;
    const int dir  = bi & 1;
    const int grp  = (bi >> 1) & 1;
    const int wg   = bi >> 2;            // 0..31
    const int gid  = dir * 2 + grp;
    const int j0   = wg * COLS;
    const int b0   = grp * ROWS;
    const int tid  = threadIdx.x;
    const int wave = tid >> 6;
    const int lane = tid & 63;
    const int nidx = lane & 15;          // B-frag col n / A-frag row m
    const int quad = lane >> 4;

    const float* W    = dir ? Wb : Wf;
    const float* bias = dir ? bb : bf;

    unsigned int* flg = (unsigned int*)(ws + WS_FLG + gid * FLGB);  // flag[w] @ 16B stride
    unsigned char* hbase = ws + WS_H + gid * 2 * HBUF;              // + parity*HBUF
    const unsigned short* xbf = (const unsigned short*)(ws + WS_X);

    // parity-double-buffered partials -> single __syncthreads per step
    __shared__ float part[2][4][4][16][17];  // parity, wave, gate, row, col (+1 pad)
    __shared__ int hsk;                      // 2-party drain handshake (waves 0/1)
    if (tid == 0) hsk = 0;

    // --- one-time: W slice as B-fragments in registers (bf16) ---
    // wave 0/1: K rows [0,256)/[256,512) of Wx; wave 2/3: rows [0,256)/[256,512) of Wh.
    short8 bfrag[8][4];
    {
        const int krow0 = (wave < 2) ? wave * 256 : 512 + (wave - 2) * 256;
        #pragma unroll
        for (int i = 0; i < 8; ++i) {
            #pragma unroll
            for (int g = 0; g < 4; ++g) {
                short8 v;
                #pragma unroll
                for (int jj = 0; jj < 8; ++jj) {
                    int krow = krow0 + i * 32 + quad * 8 + jj;
                    v[jj] = (short)f2bf(W[krow * (4 * Hz) + g * 512 + j0 + nidx]);
                }
                bfrag[i][g] = v;
            }
        }
    }

    // --- epilogue state (waves 0/1 only): 2 adjacent cols per thread ---
    const int erow = tid >> 3;           // 0..15 over waves 0/1 (tid 0..127)
    const int ec2  = (tid & 7) * 2;      // even col of the pair
    float bia[4][2];
    float creg[2] = {0.f, 0.f};
    if (wave < 2) {
        #pragma unroll
        for (int g = 0; g < 4; ++g) {
            bia[g][0] = bias[g * 512 + j0 + ec2];
            bia[g][1] = bias[g * 512 + j0 + ec2 + 1];
        }
    }
    const size_t outbase = ((size_t)(b0 + erow) * Tz) * (2 * Hz) + dir * Hz + j0 + ec2;

    for (int s = 0; s < Tz; ++s) {
        const int t   = dir ? (Tz - 1 - s) : s;
        const int par = s & 1;
        f32x4 acc[4] = {{0,0,0,0},{0,0,0,0},{0,0,0,0},{0,0,0,0}};

        if (wave < 2) {
            // x part — independent of h, overlaps consumers' polling.
            const int kb = wave * 256;
            short8 a[8];
            if (XB) {
                #pragma unroll
                for (int i = 0; i < 8; ++i) {
                    int k = kb + i * 32 + quad * 8;
                    a[i] = *(const short8*)(xbf + (((b0 + nidx) * Tz + t) * Dz + k));
                }
            } else {
                #pragma unroll
                for (int i = 0; i < 8; ++i) {
                    int k = kb + i * 32 + quad * 8;
                    const float* q = xf + (((b0 + nidx) * Tz + t) * Dz + k);
                    short8 sv;
                    #pragma unroll
                    for (int jj = 0; jj < 8; ++jj) sv[jj] = (short)f2bf(q[jj]);
                    a[i] = sv;
                }
            }
            #pragma unroll
            for (int i = 0; i < 8; ++i)
                #pragma unroll
                for (int g = 0; g < 4; ++g)
                    acc[g] = __builtin_amdgcn_mfma_f32_16x16x32_bf16(a[i], bfrag[i][g], acc[g], 0, 0, 0);
        } else {
            // h part: poll ONLY this wave's 16 producers, then load h once.
            {
                const unsigned tgt = (unsigned)s;
                const int fi = ((wave - 2) * 16 + (lane & 15)) * 4;   // 16B stride
                for (;;) {
                    unsigned f = __hip_atomic_load(flg + fi, __ATOMIC_RELAXED, __HIP_MEMORY_SCOPE_AGENT);
                    if (__ballot(f >= tgt) == ~0ull) break;
                }
            }
            const unsigned long long* hb = (const unsigned long long*)(hbase + par * HBUF);
            const int kb = (wave - 2) * 256;
            short8 a[8];
            #pragma unroll
            for (int i = 0; i < 8; ++i) {
                int k  = kb + i * 32 + quad * 8;
                int i0 = (nidx * Hz + k) >> 2;   // u64 index (4 bf16 each)
                unsigned long long l0 = __hip_atomic_load(hb + i0,     __ATOMIC_RELAXED, __HIP_MEMORY_SCOPE_AGENT);
                unsigned long long l1 = __hip_atomic_load(hb + i0 + 1, __ATOMIC_RELAXED, __HIP_MEMORY_SCOPE_AGENT);
                a[i] = mk8(l0, l1);
            }
            #pragma unroll
            for (int i = 0; i < 8; ++i)
                #pragma unroll
                for (int g = 0; g < 4; ++g)
                    acc[g] = __builtin_amdgcn_mfma_f32_16x16x32_bf16(a[i], bfrag[i][g], acc[g], 0, 0, 0);
        }

        // C/D layout: col = lane&15, row = quad*4 + reg
        {
            const int r0 = quad * 4;
            #pragma unroll
            for (int g = 0; g < 4; ++g)
                #pragma unroll
                for (int r = 0; r < 4; ++r)
                    part[par][wave][g][r0 + r][nidx] = acc[g][r];
        }
        __syncthreads();
        // Waves 2/3 fall straight through to the next step's flag poll —
        // overlapping the producers' epilogue+drain+flag tail below.

        if (wave < 2) {
            // epilogue: 2 adjacent cols per thread (no shfl needed)
            float hv[2];
            #pragma unroll
            for (int c = 0; c < 2; ++c) {
                float z[4];
                #pragma unroll
                for (int g = 0; g < 4; ++g)
                    z[g] = bia[g][c] + part[par][0][g][erow][ec2 + c] + part[par][1][g][erow][ec2 + c]
                                     + part[par][2][g][erow][ec2 + c] + part[par][3][g][erow][ec2 + c];
                float c_ = fsig(z[1]) * creg[c] + fsig(z[0]) * ftanh(z[3]);
                creg[c] = c_;
                hv[c] = fsig(z[2]) * ftanh(c_);
            }
            // packed h store (1 u32 per thread)
            {
                unsigned d = (unsigned)f2bf(hv[0]) | ((unsigned)f2bf(hv[1]) << 16);
                unsigned* hw = (unsigned*)(hbase + (par ^ 1) * HBUF);
                __hip_atomic_store(hw + erow * (Hz / 2) + ((j0 + ec2) >> 1), d,
                                   __ATOMIC_RELAXED, __HIP_MEMORY_SCOPE_AGENT);
            }
            // Drain this wave's h stores, then 2-party handshake, then flag.
            asm volatile("s_waitcnt vmcnt(0)" ::: "memory");
            if (lane == 0) atomicAdd(&hsk, 1);
            if (tid == 0) {
                while (__hip_atomic_load(&hsk, __ATOMIC_RELAXED, __HIP_MEMORY_SCOPE_WORKGROUP) < 2 * (s + 1)) {}
                __hip_atomic_store(flg + wg * 4, (unsigned)(s + 1),
                                   __ATOMIC_RELAXED, __HIP_MEMORY_SCOPE_AGENT);
            }
            // out store AFTER the flag: its HBM ack overlaps the next step.
            *(float2*)(out + outbase + (size_t)t * (2 * Hz)) = make_float2(hv[0], hv[1]);
        }
    }
}

extern "C" void kernel_launch(void* const* d_in, const int* in_sizes, int n_in,
                              void* d_out, int out_size, void* d_ws, size_t ws_size,
                              hipStream_t stream) {
    const float* x  = (const float*)d_in[0];
    const float* Wf = (const float*)d_in[1];
    const float* bf = (const float*)d_in[2];
    const float* Wb = (const float*)d_in[3];
    const float* bb = (const float*)d_in[4];
    float* out = (float*)d_out;
    unsigned char* ws = (unsigned char*)d_ws;
    const bool xb = (ws_size >= WS_NEED);

    init_kernel<<<8192, 256, 0, stream>>>(x, ws, xb ? 1 : 0);
    if (xb)
        lstm_kernel<true><<<NG * GWG, 256, 0, stream>>>(x, Wf, bf, Wb, bb, out, ws);
    else
        lstm_kernel<false><<<NG * GWG, 256, 0, stream>>>(x, Wf, bf, Wb, bb, out, ws);
}